// Round 10
// baseline (219.896 us; speedup 1.0000x reference)
//
#include <hip/hip_runtime.h>
#include <hip/hip_bf16.h>
#include <math.h>

#define B_  256
#define T_  512
#define D_  256
#define A_  50
#define EPS 1e-7f

typedef short  short8  __attribute__((ext_vector_type(8)));
typedef float  floatx4 __attribute__((ext_vector_type(4)));

__device__ inline unsigned short f2bf(float f) {
    unsigned int u = __float_as_uint(f);
    u = (u + 0x7fffu + ((u >> 16) & 1u)) >> 16;   // RNE (inputs are finite)
    return (unsigned short)u;
}

// cheap tanh: 1 - 2/(e^{2v}+1); exact at 0/±inf, ~2ulp midrange (|v|<~6 here)
__device__ inline float tanh_fast(float v) {
    return 1.0f - 2.0f / (__expf(2.0f * v) + 1.0f);
}

// ---------------------------------------------------------------------------
// Prep: swizzle W [256][50] fp32 into bf16 B-fragment order for
// mfma_f32_16x16x32_bf16, zero-padded to N=64. Fragment (nt,ks), lane l,
// element j holds B[k][n] with n = nt*16 + (l&15), k = ks*32 + (l>>4)*8 + j.
// Layout: Wf[((nt*8+ks)*64 + l)*8 + j]. Also bias/u zero-padded to 64
// (u pad = 0 kills the fake columns in the epilogue dot). [R4-verified]
// ---------------------------------------------------------------------------
__global__ void prep_kernel(const float* __restrict__ W,
                            const float* __restrict__ bias,
                            const float* __restrict__ u,
                            unsigned short* __restrict__ Wf,
                            float* __restrict__ bu64)
{
    int idx = blockIdx.x * 256 + threadIdx.x;      // 0 .. 16383
    int j  = idx & 7;
    int l  = (idx >> 3) & 63;
    int ks = (idx >> 9) & 7;
    int nt = idx >> 12;
    int n  = nt * 16 + (l & 15);
    int k  = ks * 32 + (l >> 4) * 8 + j;
    float val = (n < A_) ? W[k * A_ + n] : 0.0f;
    Wf[idx] = f2bf(val);
    if (idx < 64) {
        bu64[idx]      = (idx < A_) ? bias[idx] : 0.0f;
        bu64[64 + idx] = (idx < A_) ? u[idx]    : 0.0f;
    }
}

// pack 4 floats -> 4 bf16 (hardware v_cvt_pk_bf16_f32, RNE)
__device__ inline void pack_bf4(short8& av, int base, float fx, float fy,
                                float fz, float fw)
{
    union { __hip_bfloat162 h2; int i; } c0, c1;
    c0.h2 = __float22bfloat162_rn(make_float2(fx, fy));
    c1.h2 = __float22bfloat162_rn(make_float2(fz, fw));
    av[base + 0] = (short)(c0.i & 0xffff);
    av[base + 1] = (short)((unsigned)c0.i >> 16);
    av[base + 2] = (short)(c1.i & 0xffff);
    av[base + 3] = (short)((unsigned)c1.i >> 16);
}

// ---------------------------------------------------------------------------
// Kernel 1: scores via MFMA. 2048 blocks x 256 threads; wave w owns rows
// blk*64 + w*16 .. +16.
//  - Wf staged to LDS per block (32 KB): B-frag reads are ds_read_b128 on
//    lgkmcnt, so the vmcnt queue carries ONLY the HBM A-loads -> one stall
//    per tile instead of one per ks-step (the R6-R8 serializer).
//  - All 16 A float4s preloaded; launch_bounds(256,4) caps VGPR at 128 so
//    they stay resident. 4 blocks/CU (LDS 33 KB) = 16 waves/CU -> 256 KB
//    HBM in flight per CU.
//  - tanh_fast + shfl butterfly epilogue (m89-verified C layout
//    col=l&15, row=quad*4+r). Block partial of exp-scores -> partial[blk].
// ---------------------------------------------------------------------------
__global__ __launch_bounds__(256, 4)
void scores_kernel(const float* __restrict__ x,
                   const unsigned short* __restrict__ Wf,
                   const float* __restrict__ bu64,
                   float* __restrict__ s_out, float* __restrict__ partial)
{
    __shared__ int4  Wl[2048];     // 32 KB staged W fragments
    __shared__ float sred[64];

    const int tid  = threadIdx.x;
    const int w    = tid >> 6;
    const int l    = tid & 63;
    const int c    = l & 15;        // A-row / C-col within tile
    const int quad = l >> 4;        // k-slice / C-row-group
    const size_t rowbase = (size_t)blockIdx.x * 64 + w * 16;

    // Stage Wf -> LDS, coalesced
    {
        const int4* __restrict__ wsrc = (const int4*)Wf;
        #pragma unroll
        for (int i = 0; i < 8; i++)
            Wl[tid + i * 256] = wsrc[tid + i * 256];
    }

    const float4* __restrict__ xrow = (const float4*)(x + (rowbase + c) * D_);
    const short8* __restrict__ wl8  = (const short8*)Wl;

    float bnc[4], unc[4];
    #pragma unroll
    for (int nt = 0; nt < 4; nt++) {
        bnc[nt] = bu64[nt * 16 + c];
        unc[nt] = bu64[64 + nt * 16 + c];
    }
    __syncthreads();   // Wl ready

    // Preload the lane's entire 256B of A data: 16 independent HBM loads,
    // the ONLY vmcnt traffic in the kernel body.
    float4 pre[16];
    #pragma unroll
    for (int i = 0; i < 16; i++)
        pre[i] = xrow[(i >> 1) * 8 + quad * 2 + (i & 1)];

    floatx4 acc[4];
    #pragma unroll
    for (int nt = 0; nt < 4; nt++) acc[nt] = (floatx4){0.f, 0.f, 0.f, 0.f};

    #pragma unroll
    for (int ks = 0; ks < 8; ks++) {
        const float4 a0 = pre[2 * ks];
        const float4 a1 = pre[2 * ks + 1];
        short8 av;
        pack_bf4(av, 0, a0.x, a0.y, a0.z, a0.w);
        pack_bf4(av, 4, a1.x, a1.y, a1.z, a1.w);
        #pragma unroll
        for (int nt = 0; nt < 4; nt++) {
            const short8 bv = wl8[(nt * 8 + ks) * 64 + l];   // ds_read_b128
            acc[nt] = __builtin_amdgcn_mfma_f32_16x16x32_bf16(av, bv, acc[nt], 0, 0, 0);
        }
    }

    // Epilogue: lane holds uit[rowbase+quad*4+r][nt*16+c]
    #pragma unroll
    for (int r = 0; r < 4; r++) {
        float v = 0.0f;
        #pragma unroll
        for (int nt = 0; nt < 4; nt++)
            v += tanh_fast(acc[nt][r] + bnc[nt]) * unc[nt];
        #pragma unroll
        for (int off = 1; off < 16; off <<= 1)
            v += __shfl_xor(v, off, 16);
        if (c == 0) {
            const float s = expf(v);
            s_out[rowbase + quad * 4 + r] = s;
            sred[w * 16 + quad * 4 + r] = s;
        }
    }
    __syncthreads();
    if (tid == 0) {
        float s = 0.0f;
        #pragma unroll
        for (int i = 0; i < 64; i++) s += sred[i];
        partial[blockIdx.x] = s;   // one partial per 64 rows (8 per batch)
    }
}

// ---------------------------------------------------------------------------
// Kernel 2: pool over a t-chunk of 64. 2048 blocks = (batch, chunk q of 8).
// Wave w covers 16 t's fully unrolled (16 independent 1KB coalesced loads,
// L3-hot after scores); lane l owns float4 d-chunk l. [proven ~6.7 TB/s]
// ---------------------------------------------------------------------------
__global__ __launch_bounds__(256)
void pool_kernel(const float* __restrict__ x, const float* __restrict__ s_in,
                 const float* __restrict__ partial, float* __restrict__ pp)
{
    __shared__ float s_lds[64];
    __shared__ float part[4 * 256];

    const int tid = threadIdx.x;
    const int bb  = blockIdx.x >> 3;
    const int q   = blockIdx.x & 7;

    float den = EPS;
    #pragma unroll
    for (int i = 0; i < 8; i++) den += partial[bb * 8 + i];
    const float inv = 1.0f / den;

    if (tid < 64)
        s_lds[tid] = s_in[(size_t)bb * T_ + q * 64 + tid] * inv;
    __syncthreads();

    const int w = tid >> 6;
    const int l = tid & 63;

    const float* __restrict__ xb = x + ((size_t)bb * T_ + q * 64) * D_;
    float4 acc = make_float4(0.f, 0.f, 0.f, 0.f);

    #pragma unroll
    for (int i = 0; i < 16; i++) {
        const int t = w * 16 + i;
        float4 xv = *(const float4*)(xb + (size_t)t * D_ + l * 4);
        float sv  = s_lds[t];
        acc.x += xv.x * sv;
        acc.y += xv.y * sv;
        acc.z += xv.z * sv;
        acc.w += xv.w * sv;
    }

    part[w * 256 + l * 4 + 0] = acc.x;
    part[w * 256 + l * 4 + 1] = acc.y;
    part[w * 256 + l * 4 + 2] = acc.z;
    part[w * 256 + l * 4 + 3] = acc.w;
    __syncthreads();

    pp[(size_t)blockIdx.x * 256 + tid] =
        part[tid] + part[256 + tid] + part[512 + tid] + part[768 + tid];
}

// ---------------------------------------------------------------------------
// Kernel 3: combine the 8 t-chunk partials -> out[b,d].
// ---------------------------------------------------------------------------
__global__ __launch_bounds__(256)
void combine_kernel(const float* __restrict__ pp, float* __restrict__ out)
{
    const size_t idx = (size_t)blockIdx.x * 256 + threadIdx.x;  // b*256 + d
    const size_t b   = idx >> 8;
    const size_t d   = idx & 255;
    float o = 0.0f;
    #pragma unroll
    for (int q = 0; q < 8; q++) o += pp[(b * 8 + q) * 256 + d];
    out[idx] = o;
}

// ---------------------------------------------------------------------------
extern "C" void kernel_launch(void* const* d_in, const int* in_sizes, int n_in,
                              void* d_out, int out_size, void* d_ws, size_t ws_size,
                              hipStream_t stream)
{
    const float* x = (const float*)d_in[0];
    const float* W = (const float*)d_in[1];
    const float* b = (const float*)d_in[2];
    const float* u = (const float*)d_in[3];

    float* scores  = (float*)d_ws;                        // 131072 f
    float* partial = scores + (size_t)B_ * T_;            // 2048 f
    float* bu64    = partial + 2048;                      // 128 f
    float* pp      = bu64 + 128;                          // 524288 f
    unsigned short* Wf = (unsigned short*)(pp + (size_t)B_ * 8 * 256); // 16384 u16
    float* out     = (float*)d_out;

    prep_kernel   <<<64,   256, 0, stream>>>(W, b, u, Wf, bu64);
    scores_kernel <<<2048, 256, 0, stream>>>(x, Wf, bu64, scores, partial);
    pool_kernel   <<<2048, 256, 0, stream>>>(x, scores, partial, pp);
    combine_kernel<<<B_,   256, 0, stream>>>(pp, out);
}